// Round 9
// baseline (362.069 us; speedup 1.0000x reference)
//
#include <hip/hip_runtime.h>
#include <hip/hip_bf16.h>

typedef __attribute__((ext_vector_type(8))) short short8;       // MFMA A/B frag (8 bf16)
typedef __attribute__((ext_vector_type(4))) float f32x4;        // MFMA C/D frag
typedef __attribute__((ext_vector_type(8))) unsigned short ushort8;

#define LDS_ASYNC16(gsrc, ldst) \
  __builtin_amdgcn_global_load_lds((const __attribute__((address_space(1))) void*)(gsrc), \
                                   (__attribute__((address_space(3))) void*)(ldst), 16, 0, 0)

__device__ __forceinline__ unsigned short f2bf(float f) {
  unsigned int u = __float_as_uint(f);
  unsigned int r = (u + 0x7FFFu + ((u >> 16) & 1u)) >> 16;   // RNE
  return (unsigned short)r;
}
__device__ __forceinline__ float bf2f(unsigned short h) {
  return __uint_as_float((unsigned int)h << 16);
}

// ---------------- fused cast fp32 -> bf16, 5 tensors via z ----------------
__global__ __launch_bounds__(256) void cast5_f32_bf16(
    const float* __restrict__ i0, const float* __restrict__ i1, const float* __restrict__ i2,
    const float* __restrict__ i3, const float* __restrict__ i4,
    unsigned short* __restrict__ out) {
  const float* src[5] = {i0, i1, i2, i3, i4};
  int z = blockIdx.z;
  const float* in = src[z];
  size_t i = ((size_t)blockIdx.x * 256 + threadIdx.x) * 8;
  float4 a = *(const float4*)(in + i);
  float4 b = *(const float4*)(in + i + 4);
  ushort8 o;
  o[0] = f2bf(a.x); o[1] = f2bf(a.y); o[2] = f2bf(a.z); o[3] = f2bf(a.w);
  o[4] = f2bf(b.x); o[5] = f2bf(b.y); o[6] = f2bf(b.z); o[7] = f2bf(b.w);
  *(ushort8*)(out + (size_t)z * 2097152 + i) = o;
}

// ---- V transpose (8 heads/group) ----
__global__ __launch_bounds__(256) void transpose_v(const unsigned short* __restrict__ V,
                                                   unsigned short* __restrict__ Vt) {
  __shared__ unsigned short t[64][72];
  int slot = blockIdx.z;
  int k0 = blockIdx.x << 6, d0 = blockIdx.y << 6;
  const unsigned short* src = V + (size_t)k0 * 4096 + slot * 512 + d0;
  int rr = threadIdx.x >> 3;
  int cc = (threadIdx.x & 7) << 3;
#pragma unroll
  for (int half = 0; half < 64; half += 32) {
    int r = rr + half;
    ushort8 v = *(const ushort8*)(src + (size_t)r * 4096 + cc);
#pragma unroll
    for (int e = 0; e < 8; ++e) t[cc + e][r] = v[e];
  }
  __syncthreads();
  unsigned short* dst = Vt + ((size_t)slot * 512 + d0) * 2048 + k0;
#pragma unroll
  for (int half = 0; half < 64; half += 32) {
    int d = rr + half;
    *(ushort8*)(dst + (size_t)d * 2048 + cc) = *(const ushort8*)&t[d][cc];
  }
}

// ---------------- causal softmax, bf16 in place ----------------
__global__ __launch_bounds__(256) void softmax_causal_bf16(unsigned short* __restrict__ S) {
  int row = blockIdx.x;
  int q = row & 2047;
  unsigned short* srow = S + (size_t)row * 2048;
  int n = q + 1;
  int nW = ((q >> 7) + 1) << 7;
  int t = threadIdx.x, wave = t >> 6, lane = t & 63;
  int base = t * 8;
  ushort8 u = {};
  if (base < nW) u = *(const ushort8*)(srow + base);
  float vals[8];
  float m = -1e30f;
#pragma unroll
  for (int e = 0; e < 8; ++e) {
    float v = bf2f(u[e]);
    vals[e] = (base + e < n) ? v : -1e30f;
    m = fmaxf(m, vals[e]);
  }
#pragma unroll
  for (int off = 32; off > 0; off >>= 1) m = fmaxf(m, __shfl_xor(m, off, 64));
  __shared__ float red[8];
  if (lane == 0) red[wave] = m;
  __syncthreads();
  m = fmaxf(fmaxf(red[0], red[1]), fmaxf(red[2], red[3]));
  float s = 0.f;
#pragma unroll
  for (int e = 0; e < 8; ++e) {
    float ex = (base + e < n) ? __expf(vals[e] - m) : 0.f;
    vals[e] = ex; s += ex;
  }
#pragma unroll
  for (int off = 32; off > 0; off >>= 1) s += __shfl_xor(s, off, 64);
  if (lane == 0) red[4 + wave] = s;
  __syncthreads();
  s = red[4] + red[5] + red[6] + red[7];
  float inv = 1.0f / s;
  if (base < nW) {
    ushort8 o;
#pragma unroll
    for (int e = 0; e < 8; ++e) o[e] = f2bf(vals[e] * inv);
    *(ushort8*)(srow + base) = o;
  }
}

// ---------------- split-K reduce ----------------
__global__ __launch_bounds__(256) void reduce_k4(const float4* __restrict__ p,
                                                 float4* __restrict__ out, int n4) {
  int i = blockIdx.x * 256 + threadIdx.x;
  if (i >= n4) return;
  float4 a = p[i], b = p[i + n4], c = p[i + 2 * n4], d = p[i + 3 * n4];
  float4 o;
  o.x = (a.x + b.x) + (c.x + d.x);
  o.y = (a.y + b.y) + (c.y + d.y);
  o.z = (a.z + b.z) + (c.z + d.z);
  o.w = (a.w + b.w) + (c.w + d.w);
  out[i] = o;
}

// ============ 256x256 8-PHASE GEMM: C = A * B^T (bf16, row-major), K%128==0 ============
// 8 LDS units of 16KB: unit = {A|B} x 256 rows x 32k, unit idx (t&1)*2+kh; consumption
// unit for phase-pair q IS q. 1 half-tile staged/phase (even=A, odd=B), vmcnt(8) at odd
// phases only (4 half-tiles in flight, never drained). 2 barriers/phase, setprio on MFMA.
// Swizzle: LDS slot (g&3) holds global slot (g&3)^(row&3); readers use hi^(lr&3).
#define STG(Ptr, rb, ld, t_, kh_, ldsbase)                                            \
  do {                                                                                \
    LDS_ASYNC16((Ptr) + (size_t)((rb) + r0) * (ld) + (t_) * 64 + (kh_) * 32 + cs0,    \
                (ldsbase) + (size_t)tid * 8);                                         \
    LDS_ASYNC16((Ptr) + (size_t)((rb) + r0 + 128) * (ld) + (t_) * 64 + (kh_) * 32 + cs0, \
                (ldsbase) + (size_t)tid * 8 + 4096);                                  \
  } while (0)

#define PAIRQ(qq, I, STEADY)                                                          \
  {                                                                                   \
    const unsigned short* Au = As + (qq) * 8192;                                      \
    const unsigned short* Bu = Bs + (qq) * 8192;                                      \
    short8 af[8], bfr[2];                                                             \
    _Pragma("unroll") for (int j = 0; j < 8; ++j)                                     \
      af[j] = *(const short8*)(Au + (wm * 128 + j * 16 + lr) * 32 + sA);              \
    _Pragma("unroll") for (int j2 = 0; j2 < 2; ++j2)                                  \
      bfr[j2] = *(const short8*)(Bu + (wn * 64 + j2 * 16 + lr) * 32 + sA);            \
    if ((qq) == 0)      STG(Ap, m0, lda, 2 * (I) + 1, 1, As + 3 * 8192);              \
    else if (STEADY) {                                                                \
      if ((qq) == 1)      STG(Ap, m0, lda, 2 * (I) + 2, 0, As + 0 * 8192);            \
      else if ((qq) == 2) STG(Ap, m0, lda, 2 * (I) + 2, 1, As + 1 * 8192);            \
      else                STG(Ap, m0, lda, 2 * (I) + 3, 0, As + 2 * 8192);            \
    }                                                                                 \
    __builtin_amdgcn_s_barrier();                                                     \
    __builtin_amdgcn_s_setprio(1);                                                    \
    _Pragma("unroll") for (int j = 0; j < 8; ++j)                                     \
      _Pragma("unroll") for (int j2 = 0; j2 < 2; ++j2)                                \
        acc[j][j2] = __builtin_amdgcn_mfma_f32_16x16x32_bf16(af[j], bfr[j2], acc[j][j2], 0, 0, 0); \
    __builtin_amdgcn_s_setprio(0);                                                    \
    __builtin_amdgcn_s_barrier();                                                     \
    _Pragma("unroll") for (int j2 = 0; j2 < 2; ++j2)                                  \
      bfr[j2] = *(const short8*)(Bu + (wn * 64 + (2 + j2) * 16 + lr) * 32 + sA);      \
    if ((qq) == 0)      STG(Bp, n0, ldb, 2 * (I) + 1, 1, Bs + 3 * 8192);              \
    else if (STEADY) {                                                                \
      if ((qq) == 1)      STG(Bp, n0, ldb, 2 * (I) + 2, 0, Bs + 0 * 8192);            \
      else if ((qq) == 2) STG(Bp, n0, ldb, 2 * (I) + 2, 1, Bs + 1 * 8192);            \
      else                STG(Bp, n0, ldb, 2 * (I) + 3, 0, Bs + 2 * 8192);            \
    }                                                                                 \
    if (STEADY) { asm volatile("s_waitcnt vmcnt(8)" ::: "memory"); }                  \
    else if ((qq) == 0) { asm volatile("s_waitcnt vmcnt(8)" ::: "memory"); }          \
    else if ((qq) == 1) { asm volatile("s_waitcnt vmcnt(4)" ::: "memory"); }          \
    else if ((qq) == 2) { asm volatile("s_waitcnt vmcnt(0)" ::: "memory"); }          \
    __builtin_amdgcn_s_barrier();                                                     \
    __builtin_amdgcn_s_setprio(1);                                                    \
    _Pragma("unroll") for (int j = 0; j < 8; ++j)                                     \
      _Pragma("unroll") for (int j2 = 0; j2 < 2; ++j2)                                \
        acc[j][2 + j2] = __builtin_amdgcn_mfma_f32_16x16x32_bf16(af[j], bfr[j2], acc[j][2 + j2], 0, 0, 0); \
    __builtin_amdgcn_s_setprio(0);                                                    \
    __builtin_amdgcn_s_barrier();                                                     \
  }

template<int OUT_F32, int CSKIP>
__global__ __launch_bounds__(512, 2) void gemm8p(
    const unsigned short* __restrict__ A, const unsigned short* __restrict__ B,
    void* __restrict__ C, int K, int lda, int ldb, int ldc, int nH,
    long long sAb, long long sAh, long long sBb, long long sBh,
    long long sCb, long long sCh, float scale)
{
  __shared__ unsigned short As[4 * 8192];   // 64 KiB: units [t&1][kh]
  __shared__ unsigned short Bs[4 * 8192];   // 64 KiB
  int m0 = blockIdx.y * 256, n0 = blockIdx.x * 256;
  if (CSKIP && n0 > m0) return;
  int z = blockIdx.z;
  int zb = z / nH, zh = z - zb * nH;
  const unsigned short* Ap = A + (size_t)(zb * sAb + zh * sAh);
  const unsigned short* Bp = B + (size_t)(zb * sBb + zh * sBh);
  size_t coff = (size_t)(zb * sCb + zh * sCh);
  int tid = threadIdx.x;
  int wid = tid >> 6, lane = tid & 63;
  int wm = wid >> 2, wn = wid & 3;            // wave grid 2(M) x 4(N); per-wave 128x64
  int lr = lane & 15, hi = lane >> 4;
  int sA = ((hi ^ (lr & 3)) << 3);            // swizzled frag slot offset (elems)
  int r0 = tid >> 2;                          // staging row (0..127; +128 for 2nd load)
  int cs0 = (((tid & 3) ^ (r0 & 3)) << 3);    // inverse-swizzled source col (elems)

  int nt = K >> 6, ni = nt >> 1;              // callers guarantee K%128==0, ni>=1
  f32x4 acc[8][4] = {};

  // prologue: units 0,1,2 (tiles 0:kh0, 0:kh1, 1:kh0), A then B each
  STG(Ap, m0, lda, 0, 0, As + 0 * 8192);  STG(Bp, n0, ldb, 0, 0, Bs + 0 * 8192);
  STG(Ap, m0, lda, 0, 1, As + 1 * 8192);  STG(Bp, n0, ldb, 0, 1, Bs + 1 * 8192);
  STG(Ap, m0, lda, 1, 0, As + 2 * 8192);  STG(Bp, n0, ldb, 1, 0, Bs + 2 * 8192);
  asm volatile("s_waitcnt vmcnt(8)" ::: "memory");   // unit 0 (A+B) landed
  __builtin_amdgcn_s_barrier();

  for (int i = 0; i < ni - 1; ++i) {
    PAIRQ(0, i, 1) PAIRQ(1, i, 1) PAIRQ(2, i, 1) PAIRQ(3, i, 1)
  }
  {
    int i = ni - 1;
    PAIRQ(0, i, 0) PAIRQ(1, i, 0) PAIRQ(2, i, 0) PAIRQ(3, i, 0)
  }

#pragma unroll
  for (int m = 0; m < 8; ++m)
#pragma unroll
    for (int n = 0; n < 4; ++n)
#pragma unroll
      for (int r = 0; r < 4; ++r) {
        int row = m0 + wm * 128 + m * 16 + hi * 4 + r;
        int col = n0 + wn * 64 + n * 16 + lr;
        float v = acc[m][n][r] * scale;
        if (OUT_F32) ((float*)C)[coff + (size_t)row * ldc + col] = v;
        else ((unsigned short*)C)[coff + (size_t)row * ldc + col] = f2bf(v);
      }
}

// ---------------- m97-structure 128x128 GEMM (PV / out-proj) ----------------
template<int OUT_F32, int CSKIP, int KCLIP>
__global__ __launch_bounds__(256, 2) void gemm_bt(
    const unsigned short* __restrict__ A, const unsigned short* __restrict__ B,
    void* __restrict__ C, int K, int lda, int ldb, int ldc, int nH,
    long long sAb, long long sAh, long long sBb, long long sBh,
    long long sCb, long long sCh, float scale)
{
  __shared__ unsigned short As[128 * 64];
  __shared__ unsigned short Bs[128 * 64];
  int m0 = blockIdx.y * 128, n0 = blockIdx.x * 128;
  if (CSKIP && n0 > m0) return;
  int z = blockIdx.z;
  int zb = z / nH, zh = z - zb * nH;
  const unsigned short* Ap = A + (size_t)(zb * sAb + zh * sAh);
  const unsigned short* Bp = B + (size_t)(zb * sBb + zh * sBh);
  size_t coff = (size_t)(zb * sCb + zh * sCh);
  int tid = threadIdx.x;
  int wave = tid >> 6, lane = tid & 63;
  int kEnd = KCLIP ? min(K, m0 + 128) : K;

  int wr = (wave >> 1) * 64, wc = (wave & 1) * 64;
  int lr = lane & 15;
  int lkb = (lane >> 4) * 8;

  f32x4 acc[4][4] = {};

  for (int k0 = 0; k0 < kEnd; k0 += 64) {
#pragma unroll
    for (int it = 0; it < 4; ++it) {
      int g = it * 256 + tid;
      int r = g >> 3, c = (g & 7) << 3;
      LDS_ASYNC16(Ap + (size_t)(m0 + r) * lda + (k0 + c), As + (size_t)(it * 256 + wave * 64) * 8);
      LDS_ASYNC16(Bp + (size_t)(n0 + r) * ldb + (k0 + c), Bs + (size_t)(it * 256 + wave * 64) * 8);
    }
    __syncthreads();
#pragma unroll
    for (int kk = 0; kk < 64; kk += 32) {
      short8 a[4], b[4];
#pragma unroll
      for (int i = 0; i < 4; ++i)
        a[i] = *(const short8*)(As + (size_t)(wr + i * 16 + lr) * 64 + kk + lkb);
#pragma unroll
      for (int j = 0; j < 4; ++j)
        b[j] = *(const short8*)(Bs + (size_t)(wc + j * 16 + lr) * 64 + kk + lkb);
#pragma unroll
      for (int i = 0; i < 4; ++i)
#pragma unroll
        for (int j = 0; j < 4; ++j)
          acc[i][j] = __builtin_amdgcn_mfma_f32_16x16x32_bf16(a[i], b[j], acc[i][j], 0, 0, 0);
    }
    __syncthreads();
  }

  int orow = (lane >> 4) * 4, ocol = lane & 15;
#pragma unroll
  for (int i = 0; i < 4; ++i)
#pragma unroll
    for (int j = 0; j < 4; ++j)
#pragma unroll
      for (int r = 0; r < 4; ++r) {
        int row = m0 + wr + i * 16 + orow + r;
        int col = n0 + wc + j * 16 + ocol;
        float v = acc[i][j][r] * scale;
        if (OUT_F32) ((float*)C)[coff + (size_t)row * ldc + col] = v;
        else ((unsigned short*)C)[coff + (size_t)row * ldc + col] = f2bf(v);
      }
}

// ---------------- launcher ----------------
extern "C" void kernel_launch(void* const* d_in, const int* in_sizes, int n_in,
                              void* d_out, int out_size, void* d_ws, size_t ws_size,
                              hipStream_t stream) {
  const float* x  = (const float*)d_in[0];
  const float* Wq = (const float*)d_in[2];
  const float* Wk = (const float*)d_in[3];
  const float* Wv = (const float*)d_in[4];
  const float* Wo = (const float*)d_in[5];

  if (ws_size < (size_t)188 * (1 << 20)) return;

  char* ws = (char*)d_ws;
  unsigned short* xb   = (unsigned short*)(ws);
  unsigned short* Wob  = (unsigned short*)(ws + (size_t)16  * (1 << 20));
  unsigned short* QKV  = (unsigned short*)(ws + (size_t)20  * (1 << 20));
  unsigned short* Sc   = (unsigned short*)(ws + (size_t)116 * (1 << 20));
  unsigned short* Vt   = (unsigned short*)(ws);
  float*          Pp   = (float*)(ws + (size_t)116 * (1 << 20));

  const int NEw = 4096 * 512;
  const long long NEm = 4096LL * 4096;

  // 1) fused casts
  cast5_f32_bf16<<<dim3(1024, 1, 5), 256, 0, stream>>>(x, Wq, Wk, Wv, Wo, xb);

  // 2) QKV projection on the 8-phase engine (K=512, ni=4)
  gemm8p<0, 0><<<dim3(16, 16, 3), 512, 0, stream>>>(
      xb, xb + NEw, QKV, 512, 512, 512, 4096, 3,
      0LL, 0LL, 0LL, (long long)NEw, 0LL, NEm, 1.0f);

  // 3) attention, per batch
  for (int b = 0; b < 2; ++b) {
    size_t tokOff = (size_t)b * 2048 * 4096;
    const unsigned short* Qb = QKV + tokOff;
    const unsigned short* Kb = QKV + NEm + tokOff;
    const unsigned short* Vb = QKV + 2 * NEm + tokOff;
    unsigned short* AOb = QKV + tokOff;              // AO aliases Q

    // 3a) scores on the 8-phase engine, causal 256-tile skip
    gemm8p<0, 1><<<dim3(8, 8, 8), 512, 0, stream>>>(
        Qb, Kb, Sc, 512, 4096, 4096, 2048, 8,
        0LL, 512LL, 0LL, 512LL, 0LL, 2048LL * 2048, 0.04419417382415922f);

    // 3b) V transpose
    transpose_v<<<dim3(32, 8, 8), 256, 0, stream>>>(Vb, Vt);

    // 3c) softmax (causal) bf16 in place
    softmax_causal_bf16<<<dim3(8 * 2048), 256, 0, stream>>>(Sc);

    // 3d) O = P @ V via P * Vt^T, k clipped to m0+128 (m97 engine)
    gemm_bt<0, 0, 1><<<dim3(4, 16, 8), 256, 0, stream>>>(
        Sc, Vt, AOb, 2048, 2048, 2048, 4096, 8,
        0LL, 2048LL * 2048, 0LL, 512LL * 2048, 0LL, 512LL, 1.0f);
  }

  // 4) out-proj split-K=4 (m97 engine)
  gemm_bt<1, 0, 0><<<dim3(4, 32, 4), 256, 0, stream>>>(
      QKV, Wob, Pp, 1024, 4096, 4096, 512, 4,
      0LL, 1024LL, 0LL, 1024LL, 0LL, 2097152LL, 1.0f);

  // 5) reduce partials -> fp32 d_out
  reduce_k4<<<dim3(2048), 256, 0, stream>>>((const float4*)Pp, (float4*)d_out, 524288);
}

// Round 11
// 346.400 us; speedup vs baseline: 1.0452x; 1.0452x over previous
//
#include <hip/hip_runtime.h>
#include <hip/hip_bf16.h>

typedef __attribute__((ext_vector_type(8))) short short8;       // MFMA A/B frag (8 bf16)
typedef __attribute__((ext_vector_type(4))) float f32x4;        // MFMA C/D frag
typedef __attribute__((ext_vector_type(8))) unsigned short ushort8;

#define LDS_ASYNC16(gsrc, ldst) \
  __builtin_amdgcn_global_load_lds((const __attribute__((address_space(1))) void*)(gsrc), \
                                   (__attribute__((address_space(3))) void*)(ldst), 16, 0, 0)

__device__ __forceinline__ unsigned short f2bf(float f) {
  unsigned int u = __float_as_uint(f);
  unsigned int r = (u + 0x7FFFu + ((u >> 16) & 1u)) >> 16;   // RNE
  return (unsigned short)r;
}
__device__ __forceinline__ float bf2f(unsigned short h) {
  return __uint_as_float((unsigned int)h << 16);
}

// ---------------- fused cast fp32 -> bf16, 5 tensors via z ----------------
__global__ __launch_bounds__(256) void cast5_f32_bf16(
    const float* __restrict__ i0, const float* __restrict__ i1, const float* __restrict__ i2,
    const float* __restrict__ i3, const float* __restrict__ i4,
    unsigned short* __restrict__ out) {
  const float* src[5] = {i0, i1, i2, i3, i4};
  int z = blockIdx.z;
  const float* in = src[z];
  size_t i = ((size_t)blockIdx.x * 256 + threadIdx.x) * 8;
  float4 a = *(const float4*)(in + i);
  float4 b = *(const float4*)(in + i + 4);
  ushort8 o;
  o[0] = f2bf(a.x); o[1] = f2bf(a.y); o[2] = f2bf(a.z); o[3] = f2bf(a.w);
  o[4] = f2bf(b.x); o[5] = f2bf(b.y); o[6] = f2bf(b.z); o[7] = f2bf(b.w);
  *(ushort8*)(out + (size_t)z * 2097152 + i) = o;
}

// ---- V transpose (8 heads/group) ----
__global__ __launch_bounds__(256) void transpose_v(const unsigned short* __restrict__ V,
                                                   unsigned short* __restrict__ Vt) {
  __shared__ unsigned short t[64][72];
  int slot = blockIdx.z;
  int k0 = blockIdx.x << 6, d0 = blockIdx.y << 6;
  const unsigned short* src = V + (size_t)k0 * 4096 + slot * 512 + d0;
  int rr = threadIdx.x >> 3;
  int cc = (threadIdx.x & 7) << 3;
#pragma unroll
  for (int half = 0; half < 64; half += 32) {
    int r = rr + half;
    ushort8 v = *(const ushort8*)(src + (size_t)r * 4096 + cc);
#pragma unroll
    for (int e = 0; e < 8; ++e) t[cc + e][r] = v[e];
  }
  __syncthreads();
  unsigned short* dst = Vt + ((size_t)slot * 512 + d0) * 2048 + k0;
#pragma unroll
  for (int half = 0; half < 64; half += 32) {
    int d = rr + half;
    *(ushort8*)(dst + (size_t)d * 2048 + cc) = *(const ushort8*)&t[d][cc];
  }
}

// ---------------- causal softmax, bf16 in place ----------------
__global__ __launch_bounds__(256) void softmax_causal_bf16(unsigned short* __restrict__ S) {
  int row = blockIdx.x;
  int q = row & 2047;
  unsigned short* srow = S + (size_t)row * 2048;
  int n = q + 1;
  int nW = ((q >> 7) + 1) << 7;
  int t = threadIdx.x, wave = t >> 6, lane = t & 63;
  int base = t * 8;
  ushort8 u = {};
  if (base < nW) u = *(const ushort8*)(srow + base);
  float vals[8];
  float m = -1e30f;
#pragma unroll
  for (int e = 0; e < 8; ++e) {
    float v = bf2f(u[e]);
    vals[e] = (base + e < n) ? v : -1e30f;
    m = fmaxf(m, vals[e]);
  }
#pragma unroll
  for (int off = 32; off > 0; off >>= 1) m = fmaxf(m, __shfl_xor(m, off, 64));
  __shared__ float red[8];
  if (lane == 0) red[wave] = m;
  __syncthreads();
  m = fmaxf(fmaxf(red[0], red[1]), fmaxf(red[2], red[3]));
  float s = 0.f;
#pragma unroll
  for (int e = 0; e < 8; ++e) {
    float ex = (base + e < n) ? __expf(vals[e] - m) : 0.f;
    vals[e] = ex; s += ex;
  }
#pragma unroll
  for (int off = 32; off > 0; off >>= 1) s += __shfl_xor(s, off, 64);
  if (lane == 0) red[4 + wave] = s;
  __syncthreads();
  s = red[4] + red[5] + red[6] + red[7];
  float inv = 1.0f / s;
  if (base < nW) {
    ushort8 o;
#pragma unroll
    for (int e = 0; e < 8; ++e) o[e] = f2bf(vals[e] * inv);
    *(ushort8*)(srow + base) = o;
  }
}

// ---------------- split-K reduce ----------------
__global__ __launch_bounds__(256) void reduce_k4(const float4* __restrict__ p,
                                                 float4* __restrict__ out, int n4) {
  int i = blockIdx.x * 256 + threadIdx.x;
  if (i >= n4) return;
  float4 a = p[i], b = p[i + n4], c = p[i + 2 * n4], d = p[i + 3 * n4];
  float4 o;
  o.x = (a.x + b.x) + (c.x + d.x);
  o.y = (a.y + b.y) + (c.y + d.y);
  o.z = (a.z + b.z) + (c.z + d.z);
  o.w = (a.w + b.w) + (c.w + d.w);
  out[i] = o;
}

// ============ 256x256 unit-phase GEMM: C = A * B^T (bf16, row-major), K%32==0, K>=128 ============
// Unit = one operand x 256 rows x 32 k (16 KB). Ring of 4 units per operand (128 KiB LDS).
// Per phase: 12 ds_read (8 A-frags + 4 B-frags) || stage unit u+3 (4 gload_lds) -> barrier ->
// setprio 32-MFMA setprio -> counted vmcnt -> barrier. Steady vmcnt(8) retires unit u+1;
// tail peels vmcnt(4)/vmcnt(0)/none. Swizzle: LDS slot t holds global slot t^((row>>1)&3)
// (bank-group = (row&1)*4 + slot' -> rows 0..7 cover all 8 groups; 2-way aliasing = free).
#define STGU(u_)                                                                   \
  do {                                                                             \
    int kb_ = (u_) * 32;                                                           \
    unsigned short* Ad_ = AsBase + ((u_) & 3) * 8192 + tid * 8;                    \
    unsigned short* Bd_ = BsBase + ((u_) & 3) * 8192 + tid * 8;                    \
    LDS_ASYNC16(Ap + (size_t)(m0 + r0) * lda + kb_ + cs0, Ad_);                    \
    LDS_ASYNC16(Bp + (size_t)(n0 + r0) * ldb + kb_ + cs0, Bd_);                    \
    LDS_ASYNC16(Ap + (size_t)(m0 + r0 + 128) * lda + kb_ + cs0, Ad_ + 4096);       \
    LDS_ASYNC16(Bp + (size_t)(n0 + r0 + 128) * ldb + kb_ + cs0, Bd_ + 4096);       \
  } while (0)

#define UNITPH(u_, STAGE_, WAITOP_)                                                \
  {                                                                                \
    const unsigned short* Au = AsBase + ((u_) & 3) * 8192;                         \
    const unsigned short* Bu = BsBase + ((u_) & 3) * 8192;                         \
    short8 af[8], bf[4];                                                           \
    _Pragma("unroll") for (int j = 0; j < 8; ++j)                                  \
      af[j] = *(const short8*)(Au + (wm * 128 + j * 16 + lr) * 32 + sA);           \
    _Pragma("unroll") for (int j = 0; j < 4; ++j)                                  \
      bf[j] = *(const short8*)(Bu + (wn * 64 + j * 16 + lr) * 32 + sA);            \
    if (STAGE_) STGU((u_) + 3);                                                    \
    __builtin_amdgcn_s_barrier();                                                  \
    __builtin_amdgcn_s_setprio(1);                                                 \
    _Pragma("unroll") for (int j = 0; j < 8; ++j)                                  \
      _Pragma("unroll") for (int j2 = 0; j2 < 4; ++j2)                             \
        acc[j][j2] = __builtin_amdgcn_mfma_f32_16x16x32_bf16(af[j], bf[j2],        \
                                                             acc[j][j2], 0, 0, 0); \
    __builtin_amdgcn_s_setprio(0);                                                 \
    WAITOP_;                                                                       \
    __builtin_amdgcn_s_barrier();                                                  \
  }

template<int OUT_F32, int CSKIP>
__global__ __launch_bounds__(512, 2) void gemm8p(
    const unsigned short* __restrict__ A, const unsigned short* __restrict__ B,
    void* __restrict__ C, int K, int lda, int ldb, int ldc, int nH,
    long long sAb, long long sAh, long long sBb, long long sBh,
    long long sCb, long long sCh, float scale)
{
  __shared__ unsigned short AsBase[4 * 8192];   // 64 KiB
  __shared__ unsigned short BsBase[4 * 8192];   // 64 KiB
  int m0 = blockIdx.y * 256, n0 = blockIdx.x * 256;
  if (CSKIP && n0 > m0) return;
  int z = blockIdx.z;
  int zb = z / nH, zh = z - zb * nH;
  const unsigned short* Ap = A + (size_t)(zb * sAb + zh * sAh);
  const unsigned short* Bp = B + (size_t)(zb * sBb + zh * sBh);
  size_t coff = (size_t)(zb * sCb + zh * sCh);
  int tid = threadIdx.x;
  int wid = tid >> 6, lane = tid & 63;
  int wm = wid >> 2, wn = wid & 3;              // wave grid 2(M) x 4(N); per-wave 128x64
  int lr = lane & 15, hi = lane >> 4;
  int sA  = (hi ^ ((lr >> 1) & 3)) << 3;        // swizzled read slot (elems)
  int r0  = tid >> 2;                           // staging row (0..127; +128 second load)
  int cs0 = ((tid & 3) ^ ((r0 >> 1) & 3)) << 3; // inverse-swizzled source col (elems)

  int N = K >> 5;                               // 32-k units; callers: K%32==0, N>=4
  f32x4 acc[8][4] = {};

  STGU(0); STGU(1); STGU(2);
  asm volatile("s_waitcnt vmcnt(8)" ::: "memory");   // unit 0 landed (1,2 in flight)
  __builtin_amdgcn_s_barrier();

  for (int u = 0; u + 3 < N; ++u)
    UNITPH(u, 1, asm volatile("s_waitcnt vmcnt(8)" ::: "memory"))
  UNITPH(N - 3, 0, asm volatile("s_waitcnt vmcnt(4)" ::: "memory"))
  UNITPH(N - 2, 0, asm volatile("s_waitcnt vmcnt(0)" ::: "memory"))
  UNITPH(N - 1, 0, )

#pragma unroll
  for (int m = 0; m < 8; ++m)
#pragma unroll
    for (int n = 0; n < 4; ++n)
#pragma unroll
      for (int r = 0; r < 4; ++r) {
        int row = m0 + wm * 128 + m * 16 + hi * 4 + r;
        int col = n0 + wn * 64 + n * 16 + lr;
        float v = acc[m][n][r] * scale;
        if (OUT_F32) ((float*)C)[coff + (size_t)row * ldc + col] = v;
        else ((unsigned short*)C)[coff + (size_t)row * ldc + col] = f2bf(v);
      }
}

// ---------------- m97-structure 128x128 GEMM (PV / out-proj) ----------------
template<int OUT_F32, int CSKIP, int KCLIP>
__global__ __launch_bounds__(256, 2) void gemm_bt(
    const unsigned short* __restrict__ A, const unsigned short* __restrict__ B,
    void* __restrict__ C, int K, int lda, int ldb, int ldc, int nH,
    long long sAb, long long sAh, long long sBb, long long sBh,
    long long sCb, long long sCh, float scale)
{
  __shared__ unsigned short As[128 * 64];
  __shared__ unsigned short Bs[128 * 64];
  int m0 = blockIdx.y * 128, n0 = blockIdx.x * 128;
  if (CSKIP && n0 > m0) return;
  int z = blockIdx.z;
  int zb = z / nH, zh = z - zb * nH;
  const unsigned short* Ap = A + (size_t)(zb * sAb + zh * sAh);
  const unsigned short* Bp = B + (size_t)(zb * sBb + zh * sBh);
  size_t coff = (size_t)(zb * sCb + zh * sCh);
  int tid = threadIdx.x;
  int wave = tid >> 6, lane = tid & 63;
  int kEnd = KCLIP ? min(K, m0 + 128) : K;

  int wr = (wave >> 1) * 64, wc = (wave & 1) * 64;
  int lr = lane & 15;
  int lkb = (lane >> 4) * 8;

  f32x4 acc[4][4] = {};

  for (int k0 = 0; k0 < kEnd; k0 += 64) {
#pragma unroll
    for (int it = 0; it < 4; ++it) {
      int g = it * 256 + tid;
      int r = g >> 3, c = (g & 7) << 3;
      LDS_ASYNC16(Ap + (size_t)(m0 + r) * lda + (k0 + c), As + (size_t)(it * 256 + wave * 64) * 8);
      LDS_ASYNC16(Bp + (size_t)(n0 + r) * ldb + (k0 + c), Bs + (size_t)(it * 256 + wave * 64) * 8);
    }
    __syncthreads();
#pragma unroll
    for (int kk = 0; kk < 64; kk += 32) {
      short8 a[4], b[4];
#pragma unroll
      for (int i = 0; i < 4; ++i)
        a[i] = *(const short8*)(As + (size_t)(wr + i * 16 + lr) * 64 + kk + lkb);
#pragma unroll
      for (int j = 0; j < 4; ++j)
        b[j] = *(const short8*)(Bs + (size_t)(wc + j * 16 + lr) * 64 + kk + lkb);
#pragma unroll
      for (int i = 0; i < 4; ++i)
#pragma unroll
        for (int j = 0; j < 4; ++j)
          acc[i][j] = __builtin_amdgcn_mfma_f32_16x16x32_bf16(a[i], b[j], acc[i][j], 0, 0, 0);
    }
    __syncthreads();
  }

  int orow = (lane >> 4) * 4, ocol = lane & 15;
#pragma unroll
  for (int i = 0; i < 4; ++i)
#pragma unroll
    for (int j = 0; j < 4; ++j)
#pragma unroll
      for (int r = 0; r < 4; ++r) {
        int row = m0 + wr + i * 16 + orow + r;
        int col = n0 + wc + j * 16 + ocol;
        float v = acc[i][j][r] * scale;
        if (OUT_F32) ((float*)C)[coff + (size_t)row * ldc + col] = v;
        else ((unsigned short*)C)[coff + (size_t)row * ldc + col] = f2bf(v);
      }
}

// ---------------- launcher ----------------
extern "C" void kernel_launch(void* const* d_in, const int* in_sizes, int n_in,
                              void* d_out, int out_size, void* d_ws, size_t ws_size,
                              hipStream_t stream) {
  const float* x  = (const float*)d_in[0];
  const float* Wq = (const float*)d_in[2];
  const float* Wk = (const float*)d_in[3];
  const float* Wv = (const float*)d_in[4];
  const float* Wo = (const float*)d_in[5];

  if (ws_size < (size_t)188 * (1 << 20)) return;

  char* ws = (char*)d_ws;
  unsigned short* xb   = (unsigned short*)(ws);
  unsigned short* Wob  = (unsigned short*)(ws + (size_t)16  * (1 << 20));
  unsigned short* QKV  = (unsigned short*)(ws + (size_t)20  * (1 << 20));
  unsigned short* Sc   = (unsigned short*)(ws + (size_t)116 * (1 << 20));
  unsigned short* Vt   = (unsigned short*)(ws);
  float*          Pp   = (float*)(ws + (size_t)116 * (1 << 20));

  const int NEw = 4096 * 512;
  const long long NEm = 4096LL * 4096;

  // 1) fused casts
  cast5_f32_bf16<<<dim3(1024, 1, 5), 256, 0, stream>>>(x, Wq, Wk, Wv, Wo, xb);

  // 2) QKV projection on the unit-phase engine (K=512 -> 16 units)
  gemm8p<0, 0><<<dim3(16, 16, 3), 512, 0, stream>>>(
      xb, xb + NEw, QKV, 512, 512, 512, 4096, 3,
      0LL, 0LL, 0LL, (long long)NEw, 0LL, NEm, 1.0f);

  // 3) attention, per batch
  for (int b = 0; b < 2; ++b) {
    size_t tokOff = (size_t)b * 2048 * 4096;
    const unsigned short* Qb = QKV + tokOff;
    const unsigned short* Kb = QKV + NEm + tokOff;
    const unsigned short* Vb = QKV + 2 * NEm + tokOff;
    unsigned short* AOb = QKV + tokOff;              // AO aliases Q

    // 3a) scores on the unit-phase engine, causal 256-tile skip
    gemm8p<0, 1><<<dim3(8, 8, 8), 512, 0, stream>>>(
        Qb, Kb, Sc, 512, 4096, 4096, 2048, 8,
        0LL, 512LL, 0LL, 512LL, 0LL, 2048LL * 2048, 0.04419417382415922f);

    // 3b) V transpose
    transpose_v<<<dim3(32, 8, 8), 256, 0, stream>>>(Vb, Vt);

    // 3c) softmax (causal) bf16 in place
    softmax_causal_bf16<<<dim3(8 * 2048), 256, 0, stream>>>(Sc);

    // 3d) O = P @ V via P * Vt^T, k clipped to m0+128 (m97 engine)
    gemm_bt<0, 0, 1><<<dim3(4, 16, 8), 256, 0, stream>>>(
        Sc, Vt, AOb, 2048, 2048, 2048, 4096, 8,
        0LL, 2048LL * 2048, 0LL, 512LL * 2048, 0LL, 512LL, 1.0f);
  }

  // 4) out-proj split-K=4 (m97 engine)
  gemm_bt<1, 0, 0><<<dim3(4, 32, 4), 256, 0, stream>>>(
      QKV, Wob, Pp, 1024, 4096, 4096, 512, 4,
      0LL, 1024LL, 0LL, 1024LL, 0LL, 2097152LL, 1.0f);

  // 5) reduce partials -> fp32 d_out
  reduce_k4<<<dim3(2048), 256, 0, stream>>>((const float4*)Pp, (float4*)d_out, 524288);
}

// Round 12
// 339.599 us; speedup vs baseline: 1.0662x; 1.0200x over previous
//
#include <hip/hip_runtime.h>
#include <hip/hip_bf16.h>

typedef __attribute__((ext_vector_type(8))) short short8;       // MFMA A/B frag (8 bf16)
typedef __attribute__((ext_vector_type(4))) float f32x4;        // MFMA C/D frag
typedef __attribute__((ext_vector_type(8))) unsigned short ushort8;

#define LDS_ASYNC16(gsrc, ldst) \
  __builtin_amdgcn_global_load_lds((const __attribute__((address_space(1))) void*)(gsrc), \
                                   (__attribute__((address_space(3))) void*)(ldst), 16, 0, 0)

__device__ __forceinline__ unsigned short f2bf(float f) {
  unsigned int u = __float_as_uint(f);
  unsigned int r = (u + 0x7FFFu + ((u >> 16) & 1u)) >> 16;   // RNE
  return (unsigned short)r;
}
__device__ __forceinline__ float bf2f(unsigned short h) {
  return __uint_as_float((unsigned int)h << 16);
}

// ---------------- fused cast fp32 -> bf16, 5 tensors via z ----------------
__global__ __launch_bounds__(256) void cast5_f32_bf16(
    const float* __restrict__ i0, const float* __restrict__ i1, const float* __restrict__ i2,
    const float* __restrict__ i3, const float* __restrict__ i4,
    unsigned short* __restrict__ out) {
  const float* src[5] = {i0, i1, i2, i3, i4};
  int z = blockIdx.z;
  const float* in = src[z];
  size_t i = ((size_t)blockIdx.x * 256 + threadIdx.x) * 8;
  float4 a = *(const float4*)(in + i);
  float4 b = *(const float4*)(in + i + 4);
  ushort8 o;
  o[0] = f2bf(a.x); o[1] = f2bf(a.y); o[2] = f2bf(a.z); o[3] = f2bf(a.w);
  o[4] = f2bf(b.x); o[5] = f2bf(b.y); o[6] = f2bf(b.z); o[7] = f2bf(b.w);
  *(ushort8*)(out + (size_t)z * 2097152 + i) = o;
}

// ---- V transpose (8 heads/group) ----
__global__ __launch_bounds__(256) void transpose_v(const unsigned short* __restrict__ V,
                                                   unsigned short* __restrict__ Vt) {
  __shared__ unsigned short t[64][72];
  int slot = blockIdx.z;
  int k0 = blockIdx.x << 6, d0 = blockIdx.y << 6;
  const unsigned short* src = V + (size_t)k0 * 4096 + slot * 512 + d0;
  int rr = threadIdx.x >> 3;
  int cc = (threadIdx.x & 7) << 3;
#pragma unroll
  for (int half = 0; half < 64; half += 32) {
    int r = rr + half;
    ushort8 v = *(const ushort8*)(src + (size_t)r * 4096 + cc);
#pragma unroll
    for (int e = 0; e < 8; ++e) t[cc + e][r] = v[e];
  }
  __syncthreads();
  unsigned short* dst = Vt + ((size_t)slot * 512 + d0) * 2048 + k0;
#pragma unroll
  for (int half = 0; half < 64; half += 32) {
    int d = rr + half;
    *(ushort8*)(dst + (size_t)d * 2048 + cc) = *(const ushort8*)&t[d][cc];
  }
}

// ---------------- causal softmax, bf16 in place ----------------
__global__ __launch_bounds__(256) void softmax_causal_bf16(unsigned short* __restrict__ S) {
  int row = blockIdx.x;
  int q = row & 2047;
  unsigned short* srow = S + (size_t)row * 2048;
  int n = q + 1;
  int nW = ((q >> 7) + 1) << 7;
  int t = threadIdx.x, wave = t >> 6, lane = t & 63;
  int base = t * 8;
  ushort8 u = {};
  if (base < nW) u = *(const ushort8*)(srow + base);
  float vals[8];
  float m = -1e30f;
#pragma unroll
  for (int e = 0; e < 8; ++e) {
    float v = bf2f(u[e]);
    vals[e] = (base + e < n) ? v : -1e30f;
    m = fmaxf(m, vals[e]);
  }
#pragma unroll
  for (int off = 32; off > 0; off >>= 1) m = fmaxf(m, __shfl_xor(m, off, 64));
  __shared__ float red[8];
  if (lane == 0) red[wave] = m;
  __syncthreads();
  m = fmaxf(fmaxf(red[0], red[1]), fmaxf(red[2], red[3]));
  float s = 0.f;
#pragma unroll
  for (int e = 0; e < 8; ++e) {
    float ex = (base + e < n) ? __expf(vals[e] - m) : 0.f;
    vals[e] = ex; s += ex;
  }
#pragma unroll
  for (int off = 32; off > 0; off >>= 1) s += __shfl_xor(s, off, 64);
  if (lane == 0) red[4 + wave] = s;
  __syncthreads();
  s = red[4] + red[5] + red[6] + red[7];
  float inv = 1.0f / s;
  if (base < nW) {
    ushort8 o;
#pragma unroll
    for (int e = 0; e < 8; ++e) o[e] = f2bf(vals[e] * inv);
    *(ushort8*)(srow + base) = o;
  }
}

// ---------------- split-K reduce ----------------
__global__ __launch_bounds__(256) void reduce_k4(const float4* __restrict__ p,
                                                 float4* __restrict__ out, int n4) {
  int i = blockIdx.x * 256 + threadIdx.x;
  if (i >= n4) return;
  float4 a = p[i], b = p[i + n4], c = p[i + 2 * n4], d = p[i + 3 * n4];
  float4 o;
  o.x = (a.x + b.x) + (c.x + d.x);
  o.y = (a.y + b.y) + (c.y + d.y);
  o.z = (a.z + b.z) + (c.z + d.z);
  o.w = (a.w + b.w) + (c.w + d.w);
  out[i] = o;
}

// ==== 256x256 reg-pipelined GEMM: C = A * B^T (bf16, row-major), K FIXED = 512 ====
// Unit = operand x 256 rows x 32 k (16 KB); ring of 4/operand (128 KiB LDS). Phase u:
// {ds_read frags(u+1) -> other reg set || STGU(u+3) || MFMA(u) from pre-read regs ->
// vmcnt(4) -> ONE barrier}. ds_reads stream UNDER same-phase MFMAs (lgkm wait lands
// before next phase's MFMA) -- this is the overlap the R11 structure lacked.
// Swizzle (conflict-free, R11-proven): LDS slot t holds global slot t^((row>>1)&3).
#define STGU(u_)                                                                   \
  do {                                                                             \
    int kb_ = (u_) * 32;                                                           \
    unsigned short* Ad_ = AsBase + ((u_) & 3) * 8192 + tid * 8;                    \
    unsigned short* Bd_ = BsBase + ((u_) & 3) * 8192 + tid * 8;                    \
    LDS_ASYNC16(Ap + (size_t)(m0 + r0) * lda + kb_ + cs0, Ad_);                    \
    LDS_ASYNC16(Bp + (size_t)(n0 + r0) * ldb + kb_ + cs0, Bd_);                    \
    LDS_ASYNC16(Ap + (size_t)(m0 + r0 + 128) * lda + kb_ + cs0, Ad_ + 4096);       \
    LDS_ASYNC16(Bp + (size_t)(n0 + r0 + 128) * ldb + kb_ + cs0, Bd_ + 4096);       \
  } while (0)

#define RDFR(u_, AF, BF)                                                           \
  {                                                                                \
    const unsigned short* Au_ = AsBase + ((u_) & 3) * 8192;                        \
    const unsigned short* Bu_ = BsBase + ((u_) & 3) * 8192;                        \
    _Pragma("unroll") for (int j_ = 0; j_ < 8; ++j_)                               \
      AF[j_] = *(const short8*)(Au_ + (wm * 128 + j_ * 16 + lr) * 32 + sA);        \
    _Pragma("unroll") for (int j_ = 0; j_ < 4; ++j_)                               \
      BF[j_] = *(const short8*)(Bu_ + (wn * 64 + j_ * 16 + lr) * 32 + sA);         \
  }

#define MMAC(AF, BF)                                                               \
  __builtin_amdgcn_s_setprio(1);                                                   \
  _Pragma("unroll") for (int j_ = 0; j_ < 8; ++j_)                                 \
    _Pragma("unroll") for (int j2_ = 0; j2_ < 4; ++j2_)                            \
      acc[j_][j2_] = __builtin_amdgcn_mfma_f32_16x16x32_bf16(AF[j_], BF[j2_],      \
                                                             acc[j_][j2_], 0, 0, 0); \
  __builtin_amdgcn_s_setprio(0);

#define VMC4() asm volatile("s_waitcnt vmcnt(4)" ::: "memory")
#define VMC0() asm volatile("s_waitcnt vmcnt(0)" ::: "memory")
#define VMC8() asm volatile("s_waitcnt vmcnt(8)" ::: "memory")
#define BARR() __builtin_amdgcn_s_barrier()

template<int OUT_F32, int CSKIP>
__global__ __launch_bounds__(512, 2) void gemm8p(
    const unsigned short* __restrict__ A, const unsigned short* __restrict__ B,
    void* __restrict__ C, int K /* must be 512 */, int lda, int ldb, int ldc, int nH,
    long long sAb, long long sAh, long long sBb, long long sBh,
    long long sCb, long long sCh, float scale)
{
  __shared__ unsigned short AsBase[4 * 8192];   // 64 KiB
  __shared__ unsigned short BsBase[4 * 8192];   // 64 KiB
  int m0 = blockIdx.y * 256, n0 = blockIdx.x * 256;
  if (CSKIP && n0 > m0) return;
  int z = blockIdx.z;
  int zb = z / nH, zh = z - zb * nH;
  const unsigned short* Ap = A + (size_t)(zb * sAb + zh * sAh);
  const unsigned short* Bp = B + (size_t)(zb * sBb + zh * sBh);
  size_t coff = (size_t)(zb * sCb + zh * sCh);
  int tid = threadIdx.x;
  int wid = tid >> 6, lane = tid & 63;
  int wm = wid >> 2, wn = wid & 3;              // wave grid 2(M) x 4(N); per-wave 128x64
  int lr = lane & 15, hi = lane >> 4;
  int sA  = (hi ^ ((lr >> 1) & 3)) << 3;        // swizzled read slot (elems)
  int r0  = tid >> 2;                           // staging row (0..127; +128 second load)
  int cs0 = ((tid & 3) ^ ((r0 >> 1) & 3)) << 3; // inverse-swizzled source col (elems)

  short8 af0[8], bf0[4], af1[8], bf1[4];        // double-buffered fragment sets
  f32x4 acc[8][4] = {};

  // prologue: stage units 0,1,2; land 0; read frags(0); land 1
  STGU(0); STGU(1); STGU(2);
  VMC8(); BARR();
  RDFR(0, af0, bf0);
  VMC4(); BARR();

  // phases 0..11 (steady, unroll x2 for frag-set parity)
  for (int u = 0; u < 12; u += 2) {
    RDFR(u + 1, af1, bf1); STGU(u + 3); MMAC(af0, bf0); VMC4(); BARR();
    RDFR(u + 2, af0, bf0); STGU(u + 4); MMAC(af1, bf1); VMC4(); BARR();
  }
  // phase 12 (last stage), 13, 14, 15 (tail)
  RDFR(13, af1, bf1); STGU(15); MMAC(af0, bf0); VMC4(); BARR();
  RDFR(14, af0, bf0);           MMAC(af1, bf1); VMC0(); BARR();
  RDFR(15, af1, bf1);           MMAC(af0, bf0);         BARR();
                                MMAC(af1, bf1);

#pragma unroll
  for (int m = 0; m < 8; ++m)
#pragma unroll
    for (int n = 0; n < 4; ++n)
#pragma unroll
      for (int r = 0; r < 4; ++r) {
        int row = m0 + wm * 128 + m * 16 + hi * 4 + r;
        int col = n0 + wn * 64 + n * 16 + lr;
        float v = acc[m][n][r] * scale;
        if (OUT_F32) ((float*)C)[coff + (size_t)row * ldc + col] = v;
        else ((unsigned short*)C)[coff + (size_t)row * ldc + col] = f2bf(v);
      }
}

// ---------------- m97-structure 128x128 GEMM (PV / out-proj) ----------------
template<int OUT_F32, int CSKIP, int KCLIP>
__global__ __launch_bounds__(256, 2) void gemm_bt(
    const unsigned short* __restrict__ A, const unsigned short* __restrict__ B,
    void* __restrict__ C, int K, int lda, int ldb, int ldc, int nH,
    long long sAb, long long sAh, long long sBb, long long sBh,
    long long sCb, long long sCh, float scale)
{
  __shared__ unsigned short As[128 * 64];
  __shared__ unsigned short Bs[128 * 64];
  int m0 = blockIdx.y * 128, n0 = blockIdx.x * 128;
  if (CSKIP && n0 > m0) return;
  int z = blockIdx.z;
  int zb = z / nH, zh = z - zb * nH;
  const unsigned short* Ap = A + (size_t)(zb * sAb + zh * sAh);
  const unsigned short* Bp = B + (size_t)(zb * sBb + zh * sBh);
  size_t coff = (size_t)(zb * sCb + zh * sCh);
  int tid = threadIdx.x;
  int wave = tid >> 6, lane = tid & 63;
  int kEnd = KCLIP ? min(K, m0 + 128) : K;

  int wr = (wave >> 1) * 64, wc = (wave & 1) * 64;
  int lr = lane & 15;
  int lkb = (lane >> 4) * 8;

  f32x4 acc[4][4] = {};

  for (int k0 = 0; k0 < kEnd; k0 += 64) {
#pragma unroll
    for (int it = 0; it < 4; ++it) {
      int g = it * 256 + tid;
      int r = g >> 3, c = (g & 7) << 3;
      LDS_ASYNC16(Ap + (size_t)(m0 + r) * lda + (k0 + c), As + (size_t)(it * 256 + wave * 64) * 8);
      LDS_ASYNC16(Bp + (size_t)(n0 + r) * ldb + (k0 + c), Bs + (size_t)(it * 256 + wave * 64) * 8);
    }
    __syncthreads();
#pragma unroll
    for (int kk = 0; kk < 64; kk += 32) {
      short8 a[4], b[4];
#pragma unroll
      for (int i = 0; i < 4; ++i)
        a[i] = *(const short8*)(As + (size_t)(wr + i * 16 + lr) * 64 + kk + lkb);
#pragma unroll
      for (int j = 0; j < 4; ++j)
        b[j] = *(const short8*)(Bs + (size_t)(wc + j * 16 + lr) * 64 + kk + lkb);
#pragma unroll
      for (int i = 0; i < 4; ++i)
#pragma unroll
        for (int j = 0; j < 4; ++j)
          acc[i][j] = __builtin_amdgcn_mfma_f32_16x16x32_bf16(a[i], b[j], acc[i][j], 0, 0, 0);
    }
    __syncthreads();
  }

  int orow = (lane >> 4) * 4, ocol = lane & 15;
#pragma unroll
  for (int i = 0; i < 4; ++i)
#pragma unroll
    for (int j = 0; j < 4; ++j)
#pragma unroll
      for (int r = 0; r < 4; ++r) {
        int row = m0 + wr + i * 16 + orow + r;
        int col = n0 + wc + j * 16 + ocol;
        float v = acc[i][j][r] * scale;
        if (OUT_F32) ((float*)C)[coff + (size_t)row * ldc + col] = v;
        else ((unsigned short*)C)[coff + (size_t)row * ldc + col] = f2bf(v);
      }
}

// ---------------- launcher ----------------
extern "C" void kernel_launch(void* const* d_in, const int* in_sizes, int n_in,
                              void* d_out, int out_size, void* d_ws, size_t ws_size,
                              hipStream_t stream) {
  const float* x  = (const float*)d_in[0];
  const float* Wq = (const float*)d_in[2];
  const float* Wk = (const float*)d_in[3];
  const float* Wv = (const float*)d_in[4];
  const float* Wo = (const float*)d_in[5];

  if (ws_size < (size_t)188 * (1 << 20)) return;

  char* ws = (char*)d_ws;
  unsigned short* xb   = (unsigned short*)(ws);
  unsigned short* Wob  = (unsigned short*)(ws + (size_t)16  * (1 << 20));
  unsigned short* QKV  = (unsigned short*)(ws + (size_t)20  * (1 << 20));
  unsigned short* Sc   = (unsigned short*)(ws + (size_t)116 * (1 << 20));
  unsigned short* Vt   = (unsigned short*)(ws);
  float*          Pp   = (float*)(ws + (size_t)116 * (1 << 20));

  const int NEw = 4096 * 512;
  const long long NEm = 4096LL * 4096;

  // 1) fused casts
  cast5_f32_bf16<<<dim3(1024, 1, 5), 256, 0, stream>>>(x, Wq, Wk, Wv, Wo, xb);

  // 2) QKV projection on the reg-pipelined engine (K=512 fixed)
  gemm8p<0, 0><<<dim3(16, 16, 3), 512, 0, stream>>>(
      xb, xb + NEw, QKV, 512, 512, 512, 4096, 3,
      0LL, 0LL, 0LL, (long long)NEw, 0LL, NEm, 1.0f);

  // 3) attention, per batch
  for (int b = 0; b < 2; ++b) {
    size_t tokOff = (size_t)b * 2048 * 4096;
    const unsigned short* Qb = QKV + tokOff;
    const unsigned short* Kb = QKV + NEm + tokOff;
    const unsigned short* Vb = QKV + 2 * NEm + tokOff;
    unsigned short* AOb = QKV + tokOff;              // AO aliases Q

    // 3a) scores on the reg-pipelined engine (K=512), causal 256-tile skip
    gemm8p<0, 1><<<dim3(8, 8, 8), 512, 0, stream>>>(
        Qb, Kb, Sc, 512, 4096, 4096, 2048, 8,
        0LL, 512LL, 0LL, 512LL, 0LL, 2048LL * 2048, 0.04419417382415922f);

    // 3b) V transpose
    transpose_v<<<dim3(32, 8, 8), 256, 0, stream>>>(Vb, Vt);

    // 3c) softmax (causal) bf16 in place
    softmax_causal_bf16<<<dim3(8 * 2048), 256, 0, stream>>>(Sc);

    // 3d) O = P @ V via P * Vt^T, k clipped to m0+128 (m97 engine)
    gemm_bt<0, 0, 1><<<dim3(4, 16, 8), 256, 0, stream>>>(
        Sc, Vt, AOb, 2048, 2048, 2048, 4096, 8,
        0LL, 2048LL * 2048, 0LL, 512LL * 2048, 0LL, 512LL, 1.0f);
  }

  // 4) out-proj split-K=4 (m97 engine)
  gemm_bt<1, 0, 0><<<dim3(4, 32, 4), 256, 0, stream>>>(
      QKV, Wob, Pp, 1024, 4096, 4096, 512, 4,
      0LL, 1024LL, 0LL, 1024LL, 0LL, 2097152LL, 1.0f);

  // 5) reduce partials -> fp32 d_out
  reduce_k4<<<dim3(2048), 256, 0, stream>>>((const float4*)Pp, (float4*)d_out, 524288);
}